// Round 1
// baseline (219.898 us; speedup 1.0000x reference)
//
#include <hip/hip_runtime.h>
#include <math.h>

#define NROWS 16384
#define DDIM  2048
#define EEXP  64
#define RB    64                 // rows per block
#define KC    128                // k-columns per chunk
#define NCH   (DDIM / KC)        // 16 chunks

// LDS: W^T tiles, 3 split-levels x 16 KB per buffer, double buffered = 96 KB.
// Epilogue partials (64 KB) overlay the same array after the K loop.
#define LVL      16384
#define WBUFO(b) ((b) * 49152)

typedef short  bf16x8 __attribute__((ext_vector_type(8)));   // 8 bf16 = 4 VGPR
typedef float  f32x16 __attribute__((ext_vector_type(16)));  // 32x32 accum

union V4 { uint4 u; bf16x8 s; };

// Truncating 3-way bf16 split of two floats, packed pairwise per level.
// f = X0 + X1 + X2 + eps, |eps| <= 2^-24 |f|  (subs are exact: same-exponent tails)
static __device__ __forceinline__ void split3x2(float f0, float f1,
                                                unsigned int &p0, unsigned int &p1,
                                                unsigned int &p2) {
    unsigned int a0 = __float_as_uint(f0), b0 = __float_as_uint(f1);
    unsigned int ah = a0 & 0xffff0000u,   bh = b0 & 0xffff0000u;
    float fa1 = f0 - __uint_as_float(ah);
    float fb1 = f1 - __uint_as_float(bh);
    unsigned int a1 = __float_as_uint(fa1), b1 = __float_as_uint(fb1);
    unsigned int am = a1 & 0xffff0000u,     bm = b1 & 0xffff0000u;
    float fa2 = fa1 - __uint_as_float(am);
    float fb2 = fb1 - __uint_as_float(bm);
    p0 = (a0 >> 16) | bh;
    p1 = (a1 >> 16) | bm;
    p2 = (__float_as_uint(fa2) >> 16) | (__float_as_uint(fb2) & 0xffff0000u);
}

// 8 fp32 -> three 8-bf16 fragments (k ascending in element order)
static __device__ __forceinline__ void cvt8(float4 u, float4 v, V4 &q0, V4 &q1, V4 &q2) {
    split3x2(u.x, u.y, q0.u.x, q1.u.x, q2.u.x);
    split3x2(u.z, u.w, q0.u.y, q1.u.y, q2.u.y);
    split3x2(v.x, v.y, q0.u.z, q1.u.z, q2.u.z);
    split3x2(v.z, v.w, q0.u.w, q1.u.w, q2.u.w);
}

#define MM(ACC, A, B) ACC = __builtin_amdgcn_mfma_f32_32x32x16_bf16((A), (B), ACC, 0, 0, 0)

__global__ __launch_bounds__(512, 2)
void router_kernel(const float* __restrict__ x,
                   const float* __restrict__ W,
                   const float* __restrict__ bias_v,
                   float* __restrict__ mask_out,
                   float* __restrict__ idx_out) {
    __shared__ __align__(16) unsigned char smem[98304];

    const int tid  = threadIdx.x;
    const int lane = tid & 63;
    const int w    = __builtin_amdgcn_readfirstlane(tid >> 6);  // wave id = K-slice owner
    const int row0 = blockIdx.x * RB;
    const int l31  = lane & 31;
    const int h    = lane >> 5;

    // A operand (x) straight from global:
    // MFMA 32x32x16 A layout: row = lane&31, k = 8*(lane>>5) + j  (j = elem 0..7)
    // wave w owns k = c*KC + w*16 + h*8 + 0..7  -> 2 dwordx4 per row-tile per chunk
    const float* xp0 = x + (size_t)(row0 + l31) * DDIM + (w * 16 + h * 8);
    const float* xp1 = xp0 + (size_t)32 * DDIM;

    // W staging: thread handles e = lane, k-groups kg = w and w+8 of the chunk.
    // Global loads are fully coalesced 256B rows of W.
    const int eW = lane;
    const float* wq0 = W + (size_t)(w * 8) * EEXP + eW;
    const float* wq1 = W + (size_t)((w + 8) * 8) * EEXP + eW;
    // LDS W^T tile: [e][128 k] bf16, row = 256 B; XOR swizzle breaks the 32-way
    // column conflict (G4): byte ^= (e&7)<<4. Write 8 consecutive k as one b128.
    const int wb0 = eW * 256 + ((w * 16)       ^ ((eW & 7) << 4));
    const int wb1 = eW * 256 + (((w + 8) * 16) ^ ((eW & 7) << 4));

    // B frag read offsets: col e = et*32 + l31, k-group (2w+h); same swizzle.
    const int koff = w * 32 + h * 16;
    const int be0  = l31 * 256        + (koff ^ ((l31 & 7) << 4));
    const int be1  = (l31 + 32) * 256 + (koff ^ ((l31 & 7) << 4));

    f32x16 acc0, acc1, acc2, acc3;   // (rt,et) = (0,0) (0,1) (1,0) (1,1)
#pragma unroll
    for (int i = 0; i < 16; ++i) { acc0[i] = 0.f; acc1[i] = 0.f; acc2[i] = 0.f; acc3[i] = 0.f; }

    // ---- prologue: stage W chunk 0, prefetch x chunk 0 ----
    float wr0[8], wr1[8];
#pragma unroll
    for (int j = 0; j < 8; ++j) {
        wr0[j] = wq0[(size_t)j * EEXP];
        wr1[j] = wq1[(size_t)j * EEXP];
    }
    {
        unsigned char* d = smem + WBUFO(0);
        V4 q0, q1, q2;
        cvt8(make_float4(wr0[0],wr0[1],wr0[2],wr0[3]),
             make_float4(wr0[4],wr0[5],wr0[6],wr0[7]), q0, q1, q2);
        *(uint4*)(d + wb0) = q0.u; *(uint4*)(d + LVL + wb0) = q1.u; *(uint4*)(d + 2*LVL + wb0) = q2.u;
        cvt8(make_float4(wr1[0],wr1[1],wr1[2],wr1[3]),
             make_float4(wr1[4],wr1[5],wr1[6],wr1[7]), q0, q1, q2);
        *(uint4*)(d + wb1) = q0.u; *(uint4*)(d + LVL + wb1) = q1.u; *(uint4*)(d + 2*LVL + wb1) = q2.u;
    }
    float4 xa00 = *(const float4*)(xp0);
    float4 xa01 = *(const float4*)(xp0 + 4);
    float4 xa10 = *(const float4*)(xp1);
    float4 xa11 = *(const float4*)(xp1 + 4);
    __syncthreads();

#pragma unroll 1
    for (int c = 0; c < NCH; ++c) {
        const int  buf  = c & 1;
        const bool more = (c + 1) < NCH;

        if (more) {  // issue next W-chunk loads early (consumed at loop bottom)
            const float* q0p = wq0 + (size_t)(c + 1) * KC * EEXP;
            const float* q1p = wq1 + (size_t)(c + 1) * KC * EEXP;
#pragma unroll
            for (int j = 0; j < 8; ++j) { wr0[j] = q0p[(size_t)j * EEXP]; wr1[j] = q1p[(size_t)j * EEXP]; }
        }

        // build A fragments from x prefetched one chunk ago
        V4 a00, a10, a20, a01, a11, a21;   // aLR: split-level L, row-tile R
        cvt8(xa00, xa01, a00, a10, a20);
        cvt8(xa10, xa11, a01, a11, a21);

        if (more) {  // prefetch x for chunk c+1 (full chunk of latency cover)
            xa00 = *(const float4*)(xp0 + (c + 1) * KC);
            xa01 = *(const float4*)(xp0 + (c + 1) * KC + 4);
            xa10 = *(const float4*)(xp1 + (c + 1) * KC);
            xa11 = *(const float4*)(xp1 + (c + 1) * KC + 4);
        }

        const unsigned char* wB = smem + WBUFO(buf);
        bf16x8 b00 = *(const bf16x8*)(wB + be0);
        bf16x8 b01 = *(const bf16x8*)(wB + be1);
        bf16x8 b10 = *(const bf16x8*)(wB + LVL + be0);
        bf16x8 b11 = *(const bf16x8*)(wB + LVL + be1);
        bf16x8 b20 = *(const bf16x8*)(wB + 2 * LVL + be0);
        bf16x8 b21 = *(const bf16x8*)(wB + 2 * LVL + be1);

        // 6 significant products of the 3x3 split; round-robin over 4 acc chains
        MM(acc0, a00.s, b00); MM(acc1, a00.s, b01); MM(acc2, a01.s, b00); MM(acc3, a01.s, b01);
        MM(acc0, a00.s, b10); MM(acc1, a00.s, b11); MM(acc2, a01.s, b10); MM(acc3, a01.s, b11);
        MM(acc0, a10.s, b00); MM(acc1, a10.s, b01); MM(acc2, a11.s, b00); MM(acc3, a11.s, b01);
        MM(acc0, a00.s, b20); MM(acc1, a00.s, b21); MM(acc2, a01.s, b20); MM(acc3, a01.s, b21);
        MM(acc0, a10.s, b10); MM(acc1, a10.s, b11); MM(acc2, a11.s, b10); MM(acc3, a11.s, b11);
        MM(acc0, a20.s, b00); MM(acc1, a20.s, b01); MM(acc2, a21.s, b00); MM(acc3, a21.s, b01);

        if (more) {  // convert + write next W chunk into the other buffer
            unsigned char* d = smem + WBUFO(buf ^ 1);
            V4 q0, q1, q2;
            cvt8(make_float4(wr0[0],wr0[1],wr0[2],wr0[3]),
                 make_float4(wr0[4],wr0[5],wr0[6],wr0[7]), q0, q1, q2);
            *(uint4*)(d + wb0) = q0.u; *(uint4*)(d + LVL + wb0) = q1.u; *(uint4*)(d + 2*LVL + wb0) = q2.u;
            cvt8(make_float4(wr1[0],wr1[1],wr1[2],wr1[3]),
                 make_float4(wr1[4],wr1[5],wr1[6],wr1[7]), q0, q1, q2);
            *(uint4*)(d + wb1) = q0.u; *(uint4*)(d + LVL + wb1) = q1.u; *(uint4*)(d + 2*LVL + wb1) = q2.u;
        }
        __syncthreads();
    }

    // ---- epilogue: reduce 8 K-partials, softmax + top2 ; two 32-row phases ----
    // C/D layout (m74/m101): col = lane&31, row = (reg&3) + 8*(reg>>2) + 4*(lane>>5)
    const float bias = bias_v[lane];
    float* ep = (float*)smem;
#pragma unroll
    for (int ph = 0; ph < 2; ++ph) {
        __syncthreads();  // ph0: K-loop done; ph1: previous phase's reads done
#pragma unroll
        for (int r = 0; r < 16; ++r) {
            const int rowl = (r & 3) + 8 * (r >> 2) + 4 * h;       // 0..31
            const float va = (ph == 0) ? acc0[r] : acc2[r];        // et = 0
            const float vb = (ph == 0) ? acc1[r] : acc3[r];        // et = 1
            ep[w * 2048 + rowl * 64 + l31]      = va;
            ep[w * 2048 + rowl * 64 + l31 + 32] = vb;
        }
        __syncthreads();
#pragma unroll
        for (int rr = 0; rr < 4; ++rr) {
            const int rl  = w * 4 + rr;                 // 0..31 local row
            const int row = row0 + ph * 32 + rl;
            float logit = bias;
#pragma unroll
            for (int p = 0; p < 8; ++p) logit += ep[p * 2048 + rl * 64 + lane];

            float m = logit;
#pragma unroll
            for (int off = 32; off >= 1; off >>= 1) m = fmaxf(m, __shfl_xor(m, off));
            float ex = __expf(logit - m);
            float s = ex;
#pragma unroll
            for (int off = 32; off >= 1; off >>= 1) s += __shfl_xor(s, off);
            float gate = ex / s;

            float v1 = logit; int i1 = lane;
#pragma unroll
            for (int off = 32; off >= 1; off >>= 1) {
                float ov = __shfl_xor(v1, off);
                int   oi = __shfl_xor(i1, off);
                if (ov > v1 || (ov == v1 && oi < i1)) { v1 = ov; i1 = oi; }
            }
            float v2 = (lane == i1) ? -INFINITY : logit; int i2 = lane;
#pragma unroll
            for (int off = 32; off >= 1; off >>= 1) {
                float ov = __shfl_xor(v2, off);
                int   oi = __shfl_xor(i2, off);
                if (ov > v2 || (ov == v2 && oi < i2)) { v2 = ov; i2 = oi; }
            }

            float outv = (lane == i1 || lane == i2) ? gate : 0.0f;
            mask_out[(size_t)row * EEXP + lane] = outv;
            if (lane == 0) {
                idx_out[row * 2 + 0] = (float)i1;
                idx_out[row * 2 + 1] = (float)i2;
            }
        }
    }
}

extern "C" void kernel_launch(void* const* d_in, const int* in_sizes, int n_in,
                              void* d_out, int out_size, void* d_ws, size_t ws_size,
                              hipStream_t stream) {
    const float* x = (const float*)d_in[0];
    const float* W = (const float*)d_in[1];
    const float* b = (const float*)d_in[2];
    float* mask_out = (float*)d_out;
    float* idx_out  = mask_out + (size_t)NROWS * EEXP;

    dim3 grid(NROWS / RB);   // 256 blocks -> 1 block/CU, 8 waves/CU
    dim3 block(512);
    router_kernel<<<grid, block, 0, stream>>>(x, W, b, mask_out, idx_out);
}

// Round 2
// 218.032 us; speedup vs baseline: 1.0086x; 1.0086x over previous
//
#include <hip/hip_runtime.h>
#include <math.h>

#define NROWS 16384
#define DDIM  2048
#define EEXP  64
#define RB    32                 // rows per block -> grid 512 = 2 blocks/CU
#define KC    64                 // k-columns per chunk
#define NCH   (DDIM / KC)        // 32 chunks

// LDS: W^T tiles [e=64][k=64] bf16 = 8 KB per split-level; 3 levels = 24 KB per
// buffer, double buffered = 48 KB. Epilogue partials (32 KB) overlay afterwards.
#define LVL     8192
#define WBUF(b) ((b) * 24576)

typedef short  bf16x8 __attribute__((ext_vector_type(8)));   // 8 bf16 = 4 VGPR
typedef float  f32x16 __attribute__((ext_vector_type(16)));  // 32x32 accum

union V4 { uint4 u; bf16x8 s; };

// Truncating 3-way bf16 split of two floats, packed pairwise per level.
// f = X0 + X1 + X2 + eps, |eps| <= 2^-24 |f| (subs exact: same-exponent tails)
static __device__ __forceinline__ void split3x2(float f0, float f1,
                                                unsigned int &p0, unsigned int &p1,
                                                unsigned int &p2) {
    unsigned int a0 = __float_as_uint(f0), b0 = __float_as_uint(f1);
    unsigned int ah = a0 & 0xffff0000u,   bh = b0 & 0xffff0000u;
    float fa1 = f0 - __uint_as_float(ah);
    float fb1 = f1 - __uint_as_float(bh);
    unsigned int a1 = __float_as_uint(fa1), b1 = __float_as_uint(fb1);
    unsigned int am = a1 & 0xffff0000u,     bm = b1 & 0xffff0000u;
    float fa2 = fa1 - __uint_as_float(am);
    float fb2 = fb1 - __uint_as_float(bm);
    p0 = (a0 >> 16) | bh;
    p1 = (a1 >> 16) | bm;
    p2 = (__float_as_uint(fa2) >> 16) | (__float_as_uint(fb2) & 0xffff0000u);
}

// 8 fp32 -> three 8-bf16 fragments (k ascending in element order)
static __device__ __forceinline__ void cvt8(float4 u, float4 v, V4 &q0, V4 &q1, V4 &q2) {
    split3x2(u.x, u.y, q0.u.x, q1.u.x, q2.u.x);
    split3x2(u.z, u.w, q0.u.y, q1.u.y, q2.u.y);
    split3x2(v.x, v.y, q0.u.z, q1.u.z, q2.u.z);
    split3x2(v.z, v.w, q0.u.w, q1.u.w, q2.u.w);
}

#define MM(ACC, A, B) ACC = __builtin_amdgcn_mfma_f32_32x32x16_bf16((A), (B), ACC, 0, 0, 0)

__global__ __launch_bounds__(512, 4)
void router_kernel(const float* __restrict__ x,
                   const float* __restrict__ W,
                   const float* __restrict__ bias_v,
                   float* __restrict__ mask_out,
                   float* __restrict__ idx_out) {
    __shared__ __align__(16) unsigned char smem[49152];

    const int tid  = threadIdx.x;
    const int lane = tid & 63;
    const int w    = __builtin_amdgcn_readfirstlane(tid >> 6);
    const int kg   = w & 3;        // k16-group within chunk
    const int et   = w >> 2;       // expert half (0: e 0..31, 1: e 32..63)
    const int row0 = blockIdx.x * RB;
    const int l31  = lane & 31;
    const int h    = lane >> 5;

    // A operand (x) straight from global (MFMA 32x32x16 A: row=lane&31, k=8h+j)
    const float* xp = x + (size_t)(row0 + l31) * DDIM + kg * 16 + h * 8;

    // W staging: lane = expert e, wave w owns k rows w*8..w*8+7 of the chunk.
    // Global loads coalesce to 256B rows of W.
    const float* wq = W + (size_t)(w * 8) * EEXP + lane;
    // LDS W^T [e][64k] bf16, 128B row; 16B slot = k/8; XOR swizzle (e&7)<<4 ->
    // uniform 8 lanes per bank-quad = b128 minimum on both write and read.
    const int wb = lane * 128 + ((w * 16) ^ ((lane & 7) << 4));

    // B frag read: row r = e = et*32+l31, slot = 2*kg + h, same swizzle
    const int rB = et * 32 + l31;
    const int be = rB * 128 + (((2 * kg + h) * 16) ^ ((rB & 7) << 4));

    f32x16 acc;
#pragma unroll
    for (int i = 0; i < 16; ++i) acc[i] = 0.f;

    // ---- prologue: stage W chunk 0, prefetch x chunk 0 ----
    float wr[8];
#pragma unroll
    for (int j = 0; j < 8; ++j) wr[j] = wq[(size_t)j * EEXP];
    {
        V4 q0, q1, q2;
        cvt8(make_float4(wr[0], wr[1], wr[2], wr[3]),
             make_float4(wr[4], wr[5], wr[6], wr[7]), q0, q1, q2);
        unsigned char* d = smem + WBUF(0);
        *(uint4*)(d + wb) = q0.u;
        *(uint4*)(d + LVL + wb) = q1.u;
        *(uint4*)(d + 2 * LVL + wb) = q2.u;
    }
    float4 xlo = *(const float4*)(xp);
    float4 xhi = *(const float4*)(xp + 4);
    __syncthreads();

#pragma unroll 1
    for (int c = 0; c < NCH; ++c) {
        const int  buf  = c & 1;
        const bool more = (c + 1) < NCH;

        if (more) {  // issue next-chunk W loads early (consumed at loop bottom)
            const float* q = wq + (size_t)(c + 1) * KC * EEXP;
#pragma unroll
            for (int j = 0; j < 8; ++j) wr[j] = q[(size_t)j * EEXP];
        }

        // A fragments from x prefetched one chunk ago
        V4 a0, a1, a2;
        cvt8(xlo, xhi, a0, a1, a2);

        if (more) {  // prefetch x for chunk c+1
            xlo = *(const float4*)(xp + (c + 1) * KC);
            xhi = *(const float4*)(xp + (c + 1) * KC + 4);
        }

        const unsigned char* wB = smem + WBUF(buf);
        bf16x8 b0 = *(const bf16x8*)(wB + be);
        bf16x8 b1 = *(const bf16x8*)(wB + LVL + be);
        bf16x8 b2 = *(const bf16x8*)(wB + 2 * LVL + be);

        // 6 significant products of the 3x3 split
        MM(acc, a0.s, b0);
        MM(acc, a0.s, b1);
        MM(acc, a1.s, b0);
        MM(acc, a0.s, b2);
        MM(acc, a1.s, b1);
        MM(acc, a2.s, b0);

        if (more) {  // convert + write next W chunk into the other buffer
            V4 q0, q1, q2;
            cvt8(make_float4(wr[0], wr[1], wr[2], wr[3]),
                 make_float4(wr[4], wr[5], wr[6], wr[7]), q0, q1, q2);
            unsigned char* d = smem + WBUF(buf ^ 1);
            *(uint4*)(d + wb) = q0.u;
            *(uint4*)(d + LVL + wb) = q1.u;
            *(uint4*)(d + 2 * LVL + wb) = q2.u;
        }
        __syncthreads();   // buf[c^1] staged; also orders last reads vs epilogue
    }

    // ---- epilogue: reduce 4 kg-partials, softmax + top2 (single 32-row phase) ----
    // C/D layout (m74/m101): col = lane&31, row = (reg&3) + 8*(reg>>2) + 4*(lane>>5)
    const float bias = bias_v[lane];
    float* ep = (float*)smem;    // [kg][32 rows][64 e] = 32 KB
#pragma unroll
    for (int r = 0; r < 16; ++r) {
        const int rowl = (r & 3) + 8 * (r >> 2) + 4 * h;
        ep[kg * 2048 + rowl * 64 + et * 32 + l31] = acc[r];
    }
    __syncthreads();

#pragma unroll
    for (int rr = 0; rr < 4; ++rr) {
        const int rl  = w * 4 + rr;            // 0..31 local row
        const int row = row0 + rl;
        float logit = bias + ep[rl * 64 + lane]
                           + ep[2048 + rl * 64 + lane]
                           + ep[4096 + rl * 64 + lane]
                           + ep[6144 + rl * 64 + lane];

        float m = logit;
#pragma unroll
        for (int off = 32; off >= 1; off >>= 1) m = fmaxf(m, __shfl_xor(m, off));
        float ex = __expf(logit - m);
        float s = ex;
#pragma unroll
        for (int off = 32; off >= 1; off >>= 1) s += __shfl_xor(s, off);
        float gate = ex / s;

        float v1 = logit; int i1 = lane;
#pragma unroll
        for (int off = 32; off >= 1; off >>= 1) {
            float ov = __shfl_xor(v1, off);
            int   oi = __shfl_xor(i1, off);
            if (ov > v1 || (ov == v1 && oi < i1)) { v1 = ov; i1 = oi; }
        }
        float v2 = (lane == i1) ? -INFINITY : logit; int i2 = lane;
#pragma unroll
        for (int off = 32; off >= 1; off >>= 1) {
            float ov = __shfl_xor(v2, off);
            int   oi = __shfl_xor(i2, off);
            if (ov > v2 || (ov == v2 && oi < i2)) { v2 = ov; i2 = oi; }
        }

        float outv = (lane == i1 || lane == i2) ? gate : 0.0f;
        mask_out[(size_t)row * EEXP + lane] = outv;
        if (lane == 0) {
            idx_out[row * 2 + 0] = (float)i1;
            idx_out[row * 2 + 1] = (float)i2;
        }
    }
}

extern "C" void kernel_launch(void* const* d_in, const int* in_sizes, int n_in,
                              void* d_out, int out_size, void* d_ws, size_t ws_size,
                              hipStream_t stream) {
    const float* x = (const float*)d_in[0];
    const float* W = (const float*)d_in[1];
    const float* b = (const float*)d_in[2];
    float* mask_out = (float*)d_out;
    float* idx_out  = mask_out + (size_t)NROWS * EEXP;

    dim3 grid(NROWS / RB);   // 512 blocks -> 2 blocks/CU, 16 waves/CU
    dim3 block(512);
    router_kernel<<<grid, block, 0, stream>>>(x, W, b, mask_out, idx_out);
}